// Round 7
// baseline (771.801 us; speedup 1.0000x reference)
//
#include <hip/hip_runtime.h>
#include <hip/hip_bf16.h>
#include <cstdint>

typedef unsigned short u16;
typedef unsigned int   u32;
typedef __attribute__((ext_vector_type(8))) short bf16x8;  // 8 bf16 = 4 VGPRs
typedef __attribute__((ext_vector_type(4))) float f32x4;

#define NEG_LOG2E -1.44269504088896f

__device__ __forceinline__ float bf2f(u16 u) {
    union { u32 i; float f; } c; c.i = ((u32)u) << 16; return c.f;
}
__device__ __forceinline__ u16 f2bf(float f) {
    union { float f; u32 i; } c; c.f = f;
    u32 x = c.i;
    return (u16)((x + 0x7fffu + ((x >> 16) & 1u)) >> 16);  // RNE
}
// unpack packed bf16 pair (2 VALU: lshl + and)
__device__ __forceinline__ void bfu2(u32 p, float& lo, float& hi) {
    union { u32 i; float f; } a, b;
    a.i = p << 16; b.i = p & 0xffff0000u;
    lo = a.f; hi = b.f;
}
// gate = sigmoid(k+q) given zt = -log2e*(k+q):  rcp(1 + exp2(zt))
__device__ __forceinline__ float gate(float zt) {
    return __builtin_amdgcn_rcpf(1.0f + __builtin_amdgcn_exp2f(zt));
}

// ---------------------------------------------------------------------------
// prep: transpose+cast all 8 weight matrices (64 blocks: mat = blk>>3) and
// zero the degree histogram. Runs before hist_k / gemm.
struct P8 { const float* p[8]; };
__global__ __launch_bounds__(256)
void prep_k(P8 wsrc, u16* __restrict__ Wt, int* __restrict__ deg, int N) {
    int t = threadIdx.x;
    int mat = blockIdx.x >> 3, seg = blockIdx.x & 7;
    const float* W = wsrc.p[mat];
    u16* T = Wt + (size_t)mat * 16384;
    for (int p = 0; p < 8; ++p) {
        int idx = seg * 2048 + p * 256 + t;
        int k = idx >> 7, n = idx & 127;
        T[n * 128 + k] = f2bf(W[k * 128 + n]);
    }
    for (int i = blockIdx.x * 256 + t; i < N; i += 64 * 256) deg[i] = 0;
}

// ---------------------------------------------------------------------------
// CSR build: histogram -> single-block tiled scan -> scatter
__global__ void hist_k(const int* __restrict__ dst, int* __restrict__ deg, int nE) {
    int i  = blockIdx.x * blockDim.x + threadIdx.x;
    int st = gridDim.x * blockDim.x;
    for (; i < nE; i += st) atomicAdd(&deg[dst[i]], 1);
}

// one block, 1024 threads, 4096-elem tiles; writes rowp AND cur (= start offs)
__global__ __launch_bounds__(1024)
void scan_k(const int* __restrict__ deg, int* __restrict__ rowp,
            int* __restrict__ cur, int N, int Etot)
{
    __shared__ int wtot[16];
    __shared__ int carry;
    int t = threadIdx.x, lane = t & 63, w = t >> 6;
    if (t == 0) carry = 0;
    __syncthreads();
    for (int base = 0; base < N; base += 4096) {
        int i0 = base + t * 4;
        int d0 = (i0 + 0 < N) ? deg[i0 + 0] : 0;
        int d1 = (i0 + 1 < N) ? deg[i0 + 1] : 0;
        int d2 = (i0 + 2 < N) ? deg[i0 + 2] : 0;
        int d3 = (i0 + 3 < N) ? deg[i0 + 3] : 0;
        int s = d0 + d1 + d2 + d3;
        int ws = s;
        for (int off = 1; off < 64; off <<= 1) {
            int u = __shfl_up(ws, off);
            if (lane >= off) ws += u;
        }
        if (lane == 63) wtot[w] = ws;
        __syncthreads();
        int woff = carry;
        for (int k = 0; k < w; ++k) woff += wtot[k];
        int ex = woff + ws - s;
        if (i0 + 0 < N) { rowp[i0 + 0] = ex; cur[i0 + 0] = ex; } ex += d0;
        if (i0 + 1 < N) { rowp[i0 + 1] = ex; cur[i0 + 1] = ex; } ex += d1;
        if (i0 + 2 < N) { rowp[i0 + 2] = ex; cur[i0 + 2] = ex; } ex += d2;
        if (i0 + 3 < N) { rowp[i0 + 3] = ex; cur[i0 + 3] = ex; } ex += d3;
        __syncthreads();
        if (t == 0) {
            int tot = 0;
            for (int k = 0; k < 16; ++k) tot += wtot[k];
            carry += tot;
        }
        __syncthreads();
    }
    if (t == 0) rowp[N] = Etot;
}

__global__ void scatter_k(const int* __restrict__ src, const int* __restrict__ dst,
                          int* __restrict__ cur, int* __restrict__ ssrc, int nE) {
    int i  = blockIdx.x * blockDim.x + threadIdx.x;
    int st = gridDim.x * blockDim.x;
    for (; i < nE; i += st) {
        int pos = atomicAdd(&cur[dst[i]], 1);
        ssrc[pos] = src[i];
    }
}

// ---------------------------------------------------------------------------
// Fused GEMM (operand-swapped: A = W^T rows = out-channels, B = X rows = nodes)
//   D[ch][node] -> each lane holds 4 CONSECUTIVE channels of one node
//   KS[node][0..127]   = K~ (canonical)   KS[node][128..255] = S (canonical)
//   QV[node][g*8+0..3] = Q~[4g..4g+3]     QV[node][g*8+4..7] = V[4g..4g+3]
// F32=1: X is fp32, cast to bf16 during LDS staging (layer 1).
#define XS 136  // 128 + 8 pad -> 2-way LDS bank aliasing (free per m136)
template<int F32>
__global__ __launch_bounds__(256, 2)
void gemm_kqvs(const void* __restrict__ Xv, const u16* __restrict__ Wt,
               const float* __restrict__ bias,
               u16* __restrict__ KS, u16* __restrict__ QV, int nrows)
{
    __shared__ u16 xs[128 * XS];
    __shared__ u16 wsl[128 * XS];
    const int tid  = threadIdx.x;
    const int wave = tid >> 6, lane = tid & 63;
    const int quad = lane >> 4, l16 = lane & 15;
    const int r0 = blockIdx.x * 128;

    for (int p = 0; p < 8; ++p) {
        int c = p * 256 + tid;
        int row = c >> 4;
        int col = (c & 15) * 8;
        int gr = r0 + row; if (gr >= nrows) gr = nrows - 1;
        if (F32) {
            const float* sp = (const float*)Xv + (size_t)gr * 128 + col;
            float4 f0 = *(const float4*)(sp);
            float4 f1 = *(const float4*)(sp + 4);
            uint4 st;
            st.x = ((u32)f2bf(f0.y) << 16) | f2bf(f0.x);
            st.y = ((u32)f2bf(f0.w) << 16) | f2bf(f0.z);
            st.z = ((u32)f2bf(f1.y) << 16) | f2bf(f1.x);
            st.w = ((u32)f2bf(f1.w) << 16) | f2bf(f1.z);
            *(uint4*)(&xs[row * XS + col]) = st;
        } else {
            uint4 d = *(const uint4*)((const u16*)Xv + (size_t)gr * 128 + col);
            *(uint4*)(&xs[row * XS + col]) = d;
        }
    }

    for (int wi = 0; wi < 4; ++wi) {
        __syncthreads();
        const u16* Wsrc = Wt + wi * (128 * 128);
        for (int p = 0; p < 8; ++p) {
            int c = p * 256 + tid;
            int row = c >> 4;
            int col = (c & 15) * 8;
            uint4 d = *(const uint4*)(Wsrc + row * 128 + col);
            *(uint4*)(&wsl[row * XS + col]) = d;
        }
        __syncthreads();

        f32x4 acc[2][8];
        for (int mt = 0; mt < 2; ++mt)
            for (int nt = 0; nt < 8; ++nt) acc[mt][nt] = (f32x4)0.0f;

        const int cbase = wave * 32;  // this wave's 32 output channels
        for (int kt = 0; kt < 4; ++kt) {
            bf16x8 a0 = *(const bf16x8*)&wsl[(cbase + l16)      * XS + kt * 32 + quad * 8];
            bf16x8 a1 = *(const bf16x8*)&wsl[(cbase + 16 + l16) * XS + kt * 32 + quad * 8];
            for (int nt = 0; nt < 8; ++nt) {
                bf16x8 b = *(const bf16x8*)&xs[(nt * 16 + l16) * XS + kt * 32 + quad * 8];
                acc[0][nt] = __builtin_amdgcn_mfma_f32_16x16x32_bf16(a0, b, acc[0][nt], 0, 0, 0);
                acc[1][nt] = __builtin_amdgcn_mfma_f32_16x16x32_bf16(a1, b, acc[1][nt], 0, 0, 0);
            }
        }

        float4 bias4[2];
        if (wi == 3) {
            bias4[0] = *(const float4*)(bias + cbase + quad * 4);
            bias4[1] = *(const float4*)(bias + cbase + 16 + quad * 4);
        }
        for (int mt = 0; mt < 2; ++mt) {
            int chb = cbase + mt * 16 + quad * 4;
            for (int nt = 0; nt < 8; ++nt) {
                int node = r0 + nt * 16 + l16;
                if (node >= nrows) continue;
                f32x4 v = acc[mt][nt];
                float x0 = v[0], x1 = v[1], x2 = v[2], x3 = v[3];
                if (wi == 0 || wi == 1) {
                    x0 *= NEG_LOG2E; x1 *= NEG_LOG2E; x2 *= NEG_LOG2E; x3 *= NEG_LOG2E;
                } else if (wi == 3) {
                    x0 += bias4[mt].x; x1 += bias4[mt].y;
                    x2 += bias4[mt].z; x3 += bias4[mt].w;
                }
                uint2 st;
                st.x = ((u32)f2bf(x1) << 16) | f2bf(x0);
                st.y = ((u32)f2bf(x3) << 16) | f2bf(x2);
                size_t nb = (size_t)node * 256;
                if      (wi == 0) *(uint2*)(KS + nb + chb) = st;
                else if (wi == 3) *(uint2*)(KS + nb + 128 + chb) = st;
                else if (wi == 1) *(uint2*)(QV + nb + 2 * chb) = st;
                else              *(uint2*)(QV + nb + 2 * chb + 4) = st;
            }
        }
    }
}

// ---------------------------------------------------------------------------
// CSR gather-reduce edge phase: one wave per dst node, TWO edges per load
// (half-wave per edge, lane covers 4 channels via one dwordx4 row load).
// MLP=2 (best measured config). MODE 0: relu row -> Xout. MODE 1: fused gemv3.
template<int MODE>
__global__ __launch_bounds__(256)
void edge_csr2(const int* __restrict__ rowp, const int* __restrict__ ssrc,
               const u16* __restrict__ KS, const u16* __restrict__ QV,
               u16* __restrict__ Xout,
               const float* __restrict__ Wk3, const float* __restrict__ Wq3,
               const float* __restrict__ Wv3, const float* __restrict__ Ws3,
               const float* __restrict__ b3,
               float* __restrict__ k3, float2* __restrict__ qv3,
               float* __restrict__ s3, int N)
{
    const int lane = threadIdx.x & 63;
    const int half = lane >> 5;
    const int t    = lane & 31;       // channel group: channels 4t..4t+3
    int gw = blockIdx.x * (blockDim.x >> 6) + (threadIdx.x >> 6);
    int nw = gridDim.x * (blockDim.x >> 6);

    float4 wk4, wq4, wv4, ws4;
    float bias3 = 0.0f;
    if (MODE == 1) {
        wk4 = *(const float4*)(Wk3 + 4 * t);
        wq4 = *(const float4*)(Wq3 + 4 * t);
        wv4 = *(const float4*)(Wv3 + 4 * t);
        ws4 = *(const float4*)(Ws3 + 4 * t);
        bias3 = b3[0];
    }

#define LOAD2(S0, S1) (*((const uint4*)(QV + (size_t)(half ? (S1) : (S0)) * 256) + t))
#define COMP(QVv, A0, A1, A2, A3)                                             \
    {                                                                         \
        float q0_, q1_, q2_, q3_, v0_, v1_, v2_, v3_;                         \
        bfu2((QVv).x, q0_, q1_); bfu2((QVv).y, q2_, q3_);                     \
        bfu2((QVv).z, v0_, v1_); bfu2((QVv).w, v2_, v3_);                     \
        A0 += gate(k0 + q0_) * v0_;  A1 += gate(k1 + q1_) * v1_;              \
        A2 += gate(k2 + q2_) * v2_;  A3 += gate(k3v + q3_) * v3_;             \
    }

    for (int d = gw; d < N; d += nw) {
        int beg = rowp[d], end = rowp[d + 1];
        uint2 kk = *(const uint2*)(KS + (size_t)d * 256 + t * 4);
        float k0, k1, k2, k3v;
        bfu2(kk.x, k0, k1); bfu2(kk.y, k2, k3v);
        float a0 = 0.f, a1 = 0.f, a2 = 0.f, a3 = 0.f;
        float e0 = 0.f, e1 = 0.f, e2 = 0.f, e3 = 0.f;

        for (int base = beg; base < end; base += 64) {
            int e = base + lane;
            int sv = (e < end) ? ssrc[e] : 0;
            int m = end - base; if (m > 64) m = 64;
            int j = 0;
            for (; j + 4 <= m; j += 4) {
                int sa0 = __builtin_amdgcn_readlane(sv, j);
                int sa1 = __builtin_amdgcn_readlane(sv, j + 1);
                int sb0 = __builtin_amdgcn_readlane(sv, j + 2);
                int sb1 = __builtin_amdgcn_readlane(sv, j + 3);
                uint4 qA = LOAD2(sa0, sa1);
                uint4 qB = LOAD2(sb0, sb1);
                COMP(qA, a0, a1, a2, a3);
                COMP(qB, e0, e1, e2, e3);
            }
            if (j + 2 <= m) {
                int s0 = __builtin_amdgcn_readlane(sv, j);
                int s1 = __builtin_amdgcn_readlane(sv, j + 1);
                uint4 qA = LOAD2(s0, s1);
                COMP(qA, a0, a1, a2, a3);
                j += 2;
            }
            if (j < m) {  // single odd edge: only half 0 accumulates
                int s0i = __builtin_amdgcn_readlane(sv, j);
                uint4 qv_ = *((const uint4*)(QV + (size_t)s0i * 256) + t);
                float q0_, q1_, q2_, q3_, v0_, v1_, v2_, v3_;
                bfu2(qv_.x, q0_, q1_); bfu2(qv_.y, q2_, q3_);
                bfu2(qv_.z, v0_, v1_); bfu2(qv_.w, v2_, v3_);
                if (half == 0) {
                    a0 += gate(k0 + q0_) * v0_;  a1 += gate(k1 + q1_) * v1_;
                    a2 += gate(k2 + q2_) * v2_;  a3 += gate(k3v + q3_) * v3_;
                }
            }
        }
#undef LOAD2
#undef COMP

        a0 += e0; a1 += e1; a2 += e2; a3 += e3;
        a0 += __shfl_xor(a0, 32);
        a1 += __shfl_xor(a1, 32);
        a2 += __shfl_xor(a2, 32);
        a3 += __shfl_xor(a3, 32);

        uint2 ss = *(const uint2*)(KS + (size_t)d * 256 + 128 + t * 4);
        float s0f, s1f, s2f, s3f;
        bfu2(ss.x, s0f, s1f); bfu2(ss.y, s2f, s3f);
        float r0 = fmaxf(s0f + a0, 0.f);
        float r1 = fmaxf(s1f + a1, 0.f);
        float r2 = fmaxf(s2f + a2, 0.f);
        float r3 = fmaxf(s3f + a3, 0.f);

        if (MODE == 0) {
            if (half == 0) {
                uint2 st;
                st.x = ((u32)f2bf(r1) << 16) | f2bf(r0);
                st.y = ((u32)f2bf(r3) << 16) | f2bf(r2);
                *(uint2*)(Xout + (size_t)d * 128 + t * 4) = st;
            }
        } else {
            float pk = r0 * wk4.x + r1 * wk4.y + r2 * wk4.z + r3 * wk4.w;
            float pq = r0 * wq4.x + r1 * wq4.y + r2 * wq4.z + r3 * wq4.w;
            float pv = r0 * wv4.x + r1 * wv4.y + r2 * wv4.z + r3 * wv4.w;
            float ps = r0 * ws4.x + r1 * ws4.y + r2 * ws4.z + r3 * ws4.w;
            for (int off = 1; off < 32; off <<= 1) {
                pk += __shfl_xor(pk, off);
                pq += __shfl_xor(pq, off);
                pv += __shfl_xor(pv, off);
                ps += __shfl_xor(ps, off);
            }
            if (lane == 0) {
                k3[d]  = NEG_LOG2E * pk;
                qv3[d] = make_float2(NEG_LOG2E * pq, pv);
                s3[d]  = ps + bias3;
            }
        }
    }
}

// ---------------------------------------------------------------------------
// CSR edge phase, Dout=1: wave per node; qv3 packed float2 (one 8B gather).
__global__ __launch_bounds__(256)
void edge3_csr(const int* __restrict__ rowp, const int* __restrict__ ssrc,
               const float* __restrict__ k3, const float2* __restrict__ qv3,
               const float* __restrict__ s3, float* __restrict__ outp, int N)
{
    int lane = threadIdx.x & 63;
    int gw = blockIdx.x * (blockDim.x >> 6) + (threadIdx.x >> 6);
    int nw = gridDim.x * (blockDim.x >> 6);
    for (int d = gw; d < N; d += nw) {
        int beg = rowp[d], end = rowp[d + 1];
        float kd = k3[d];
        float sum = 0.0f;
        for (int e = beg + lane; e < end; e += 64) {
            float2 qv = qv3[ssrc[e]];
            sum += gate(kd + qv.x) * qv.y;
        }
        for (int off = 32; off > 0; off >>= 1) sum += __shfl_xor(sum, off);
        if (lane == 0) outp[d] = s3[d] + sum;
    }
}

// ---------------------------------------------------------------------------
extern "C" void kernel_launch(void* const* d_in, const int* in_sizes, int n_in,
                              void* d_out, int out_size, void* d_ws, size_t ws_size,
                              hipStream_t stream)
{
    const float* x0 = (const float*)d_in[0];
    const int*   ei = (const int*)d_in[1];
    const int    N  = in_sizes[0] / 128;   // 100000
    const int    E  = in_sizes[1] / 2;     // 1600000
    const int* src = ei;
    const int* dst = ei + E;

    char* ws = (char*)d_ws;
    size_t off = 0;
    auto carve = [&](size_t bytes) { void* p = ws + off; off += (bytes + 255) & ~(size_t)255; return p; };
    u16*    Wt   = (u16*)carve((size_t)8 * 16384 * sizeof(u16));
    u16*    bufX = (u16*)carve((size_t)N * 128 * sizeof(u16));
    u16*    KS   = (u16*)carve((size_t)N * 256 * sizeof(u16));
    u16*    QV   = (u16*)carve((size_t)N * 256 * sizeof(u16));
    int*    ssrc = (int*)carve((size_t)E * sizeof(int));
    int*    rowp = (int*)carve((size_t)(N + 1) * sizeof(int));
    int*    deg  = (int*)carve((size_t)N * sizeof(int));
    int*    cur  = (int*)carve((size_t)N * sizeof(int));
    float*  k3   = (float*)carve((size_t)N * sizeof(float));
    float2* qv3  = (float2*)carve((size_t)N * sizeof(float2));
    float*  s3   = (float*)carve((size_t)N * sizeof(float));

    // --- prep: weight transpose + deg zero (one kernel) ---
    P8 wp;
    wp.p[0] = (const float*)d_in[2];  wp.p[1] = (const float*)d_in[3];
    wp.p[2] = (const float*)d_in[4];  wp.p[3] = (const float*)d_in[5];
    wp.p[4] = (const float*)d_in[7];  wp.p[5] = (const float*)d_in[8];
    wp.p[6] = (const float*)d_in[9];  wp.p[7] = (const float*)d_in[10];
    prep_k<<<64, 256, 0, stream>>>(wp, Wt, deg, N);

    // --- CSR build ---
    hist_k<<<2048, 256, 0, stream>>>(dst, deg, E);
    scan_k<<<1, 1024, 0, stream>>>(deg, rowp, cur, N, E);
    scatter_k<<<2048, 256, 0, stream>>>(src, dst, cur, ssrc, E);

    int gb = (N + 127) / 128;

    // layer 1 (reads fp32 x directly, casts in staging)
    gemm_kqvs<1><<<gb, 256, 0, stream>>>(x0, Wt, (const float*)d_in[6], KS, QV, N);
    edge_csr2<0><<<4096, 256, 0, stream>>>(rowp, ssrc, KS, QV, bufX,
        nullptr, nullptr, nullptr, nullptr, nullptr, nullptr, nullptr, nullptr, N);
    // layer 2 (+ fused layer-3 GEMV)
    gemm_kqvs<0><<<gb, 256, 0, stream>>>(bufX, Wt + 4 * 16384, (const float*)d_in[11], KS, QV, N);
    edge_csr2<1><<<4096, 256, 0, stream>>>(rowp, ssrc, KS, QV, nullptr,
        (const float*)d_in[12], (const float*)d_in[13], (const float*)d_in[14],
        (const float*)d_in[15], (const float*)d_in[16],
        k3, qv3, s3, N);
    // layer 3 edge pass -> d_out
    edge3_csr<<<1024, 256, 0, stream>>>(rowp, ssrc, k3, qv3, s3, (float*)d_out, N);
}

// Round 8
// 698.404 us; speedup vs baseline: 1.1051x; 1.1051x over previous
//
#include <hip/hip_runtime.h>
#include <hip/hip_bf16.h>
#include <cstdint>

typedef unsigned short u16;
typedef unsigned int   u32;
typedef __attribute__((ext_vector_type(8))) short bf16x8;  // 8 bf16 = 4 VGPRs
typedef __attribute__((ext_vector_type(4))) float f32x4;

#define NEG_LOG2E -1.44269504088896f

__device__ __forceinline__ float bf2f(u16 u) {
    union { u32 i; float f; } c; c.i = ((u32)u) << 16; return c.f;
}
__device__ __forceinline__ u16 f2bf(float f) {
    union { float f; u32 i; } c; c.f = f;
    u32 x = c.i;
    return (u16)((x + 0x7fffu + ((x >> 16) & 1u)) >> 16);  // RNE
}
// unpack packed bf16 pair (2 VALU: lshl + and)
__device__ __forceinline__ void bfu2(u32 p, float& lo, float& hi) {
    union { u32 i; float f; } a, b;
    a.i = p << 16; b.i = p & 0xffff0000u;
    lo = a.f; hi = b.f;
}
// gate = sigmoid(k+q) given zt = -log2e*(k+q):  rcp(1 + exp2(zt))
__device__ __forceinline__ float gate(float zt) {
    return __builtin_amdgcn_rcpf(1.0f + __builtin_amdgcn_exp2f(zt));
}

// ---------------------------------------------------------------------------
// prep: transpose+cast all 8 weight matrices (64 blocks: mat = blk>>3) and
// zero the degree histogram. Runs before hist_k / gemm.
struct P8 { const float* p[8]; };
__global__ __launch_bounds__(256)
void prep_k(P8 wsrc, u16* __restrict__ Wt, int* __restrict__ deg, int N) {
    int t = threadIdx.x;
    int mat = blockIdx.x >> 3, seg = blockIdx.x & 7;
    const float* W = wsrc.p[mat];
    u16* T = Wt + (size_t)mat * 16384;
    for (int p = 0; p < 8; ++p) {
        int idx = seg * 2048 + p * 256 + t;
        int k = idx >> 7, n = idx & 127;
        T[n * 128 + k] = f2bf(W[k * 128 + n]);
    }
    for (int i = blockIdx.x * 256 + t; i < N; i += 64 * 256) deg[i] = 0;
}

// ---------------------------------------------------------------------------
// CSR build: histogram -> parallel 3-phase exclusive scan -> batched scatter
__global__ void hist_k(const int* __restrict__ dst, int* __restrict__ deg, int nE) {
    int i  = blockIdx.x * blockDim.x + threadIdx.x;
    int st = gridDim.x * blockDim.x;
    for (; i < nE; i += st) atomicAdd(&deg[dst[i]], 1);
}

// phase 1: per-block (1024-elem chunk, 256 thr x int4) total
__global__ __launch_bounds__(256)
void scan_part_k(const int* __restrict__ deg, int* __restrict__ part, int N) {
    __shared__ int wsum[4];
    int t = threadIdx.x, lane = t & 63, wave = t >> 6;
    int i0 = blockIdx.x * 1024 + t * 4;
    int s = 0;
    for (int j = 0; j < 4; ++j) { int i = i0 + j; if (i < N) s += deg[i]; }
    for (int off = 32; off > 0; off >>= 1) s += __shfl_xor(s, off);
    if (lane == 0) wsum[wave] = s;
    __syncthreads();
    if (t == 0) part[blockIdx.x] = wsum[0] + wsum[1] + wsum[2] + wsum[3];
}

// phase 2: one block scans the (<=128) block totals -> exclusive offsets
__global__ __launch_bounds__(128)
void scan_tops_k(int* __restrict__ part, int nb) {
    __shared__ int sh[128];
    int t = threadIdx.x;
    int v = (t < nb) ? part[t] : 0;
    sh[t] = v;
    __syncthreads();
    for (int off = 1; off < 128; off <<= 1) {
        int u = (t >= off) ? sh[t - off] : 0;
        __syncthreads();
        sh[t] += u;
        __syncthreads();
    }
    if (t < nb) part[t] = sh[t] - v;  // exclusive
}

// phase 3: re-scan chunk locally, add block offset, emit row_ptr AND cur
__global__ __launch_bounds__(256)
void scan_emit_k(const int* __restrict__ deg, const int* __restrict__ part,
                 int* __restrict__ row_ptr, int* __restrict__ cur, int N, int Etot) {
    __shared__ int woff[4];
    int t = threadIdx.x, lane = t & 63, wave = t >> 6;
    int i0 = blockIdx.x * 1024 + t * 4;
    int d[4]; int s = 0;
    for (int j = 0; j < 4; ++j) { int i = i0 + j; d[j] = (i < N) ? deg[i] : 0; s += d[j]; }
    int ws = s;
    for (int off = 1; off < 64; off <<= 1) {
        int u = __shfl_up(ws, off);
        if (lane >= off) ws += u;
    }
    if (lane == 63) woff[wave] = ws;
    __syncthreads();
    int base = part[blockIdx.x];
    for (int w = 0; w < wave; ++w) base += woff[w];
    int ex = base + ws - s;
    for (int j = 0; j < 4; ++j) {
        int i = i0 + j;
        if (i < N) { row_ptr[i] = ex; cur[i] = ex; }
        ex += d[j];
    }
    if (blockIdx.x == 0 && t == 0) row_ptr[N] = Etot;
}

// batched scatter: 4 independent atomic-with-return in flight per thread
__global__ __launch_bounds__(256)
void scatter_k(const int* __restrict__ src, const int* __restrict__ dst,
               int* __restrict__ cur, int* __restrict__ ssrc, int nE) {
    int tid = blockIdx.x * blockDim.x + threadIdx.x;
    int st  = gridDim.x * blockDim.x * 4;
    for (int i = tid * 4; i < nE; i += st) {
        if (i + 4 <= nE) {
            int4 d4 = *(const int4*)(dst + i);
            int4 s4 = *(const int4*)(src + i);
            int p0 = atomicAdd(&cur[d4.x], 1);
            int p1 = atomicAdd(&cur[d4.y], 1);
            int p2 = atomicAdd(&cur[d4.z], 1);
            int p3 = atomicAdd(&cur[d4.w], 1);
            ssrc[p0] = s4.x; ssrc[p1] = s4.y; ssrc[p2] = s4.z; ssrc[p3] = s4.w;
        } else {
            for (int j = i; j < nE; ++j) {
                int pos = atomicAdd(&cur[dst[j]], 1);
                ssrc[pos] = src[j];
            }
        }
    }
}

// ---------------------------------------------------------------------------
// Fused GEMM (operand-swapped: A = W^T rows = out-channels, B = X rows = nodes)
//   D[ch][node] -> each lane holds 4 CONSECUTIVE channels of one node
//   KS[node][0..127]   = K~ (canonical)   KS[node][128..255] = S (canonical)
//   QV[node][g*8+0..3] = Q~[4g..4g+3]     QV[node][g*8+4..7] = V[4g..4g+3]
// F32=1: X is fp32, cast to bf16 during LDS staging (layer 1).
#define XS 136  // 128 + 8 pad -> 2-way LDS bank aliasing (free per m136)
template<int F32>
__global__ __launch_bounds__(256, 2)
void gemm_kqvs(const void* __restrict__ Xv, const u16* __restrict__ Wt,
               const float* __restrict__ bias,
               u16* __restrict__ KS, u16* __restrict__ QV, int nrows)
{
    __shared__ u16 xs[128 * XS];
    __shared__ u16 wsl[128 * XS];
    const int tid  = threadIdx.x;
    const int wave = tid >> 6, lane = tid & 63;
    const int quad = lane >> 4, l16 = lane & 15;
    const int r0 = blockIdx.x * 128;

    for (int p = 0; p < 8; ++p) {
        int c = p * 256 + tid;
        int row = c >> 4;
        int col = (c & 15) * 8;
        int gr = r0 + row; if (gr >= nrows) gr = nrows - 1;
        if (F32) {
            const float* sp = (const float*)Xv + (size_t)gr * 128 + col;
            float4 f0 = *(const float4*)(sp);
            float4 f1 = *(const float4*)(sp + 4);
            uint4 st;
            st.x = ((u32)f2bf(f0.y) << 16) | f2bf(f0.x);
            st.y = ((u32)f2bf(f0.w) << 16) | f2bf(f0.z);
            st.z = ((u32)f2bf(f1.y) << 16) | f2bf(f1.x);
            st.w = ((u32)f2bf(f1.w) << 16) | f2bf(f1.z);
            *(uint4*)(&xs[row * XS + col]) = st;
        } else {
            uint4 d = *(const uint4*)((const u16*)Xv + (size_t)gr * 128 + col);
            *(uint4*)(&xs[row * XS + col]) = d;
        }
    }

    for (int wi = 0; wi < 4; ++wi) {
        __syncthreads();
        const u16* Wsrc = Wt + wi * (128 * 128);
        for (int p = 0; p < 8; ++p) {
            int c = p * 256 + tid;
            int row = c >> 4;
            int col = (c & 15) * 8;
            uint4 d = *(const uint4*)(Wsrc + row * 128 + col);
            *(uint4*)(&wsl[row * XS + col]) = d;
        }
        __syncthreads();

        f32x4 acc[2][8];
        for (int mt = 0; mt < 2; ++mt)
            for (int nt = 0; nt < 8; ++nt) acc[mt][nt] = (f32x4)0.0f;

        const int cbase = wave * 32;  // this wave's 32 output channels
        for (int kt = 0; kt < 4; ++kt) {
            bf16x8 a0 = *(const bf16x8*)&wsl[(cbase + l16)      * XS + kt * 32 + quad * 8];
            bf16x8 a1 = *(const bf16x8*)&wsl[(cbase + 16 + l16) * XS + kt * 32 + quad * 8];
            for (int nt = 0; nt < 8; ++nt) {
                bf16x8 b = *(const bf16x8*)&xs[(nt * 16 + l16) * XS + kt * 32 + quad * 8];
                acc[0][nt] = __builtin_amdgcn_mfma_f32_16x16x32_bf16(a0, b, acc[0][nt], 0, 0, 0);
                acc[1][nt] = __builtin_amdgcn_mfma_f32_16x16x32_bf16(a1, b, acc[1][nt], 0, 0, 0);
            }
        }

        float4 bias4[2];
        if (wi == 3) {
            bias4[0] = *(const float4*)(bias + cbase + quad * 4);
            bias4[1] = *(const float4*)(bias + cbase + 16 + quad * 4);
        }
        for (int mt = 0; mt < 2; ++mt) {
            int chb = cbase + mt * 16 + quad * 4;
            for (int nt = 0; nt < 8; ++nt) {
                int node = r0 + nt * 16 + l16;
                if (node >= nrows) continue;
                f32x4 v = acc[mt][nt];
                float x0 = v[0], x1 = v[1], x2 = v[2], x3 = v[3];
                if (wi == 0 || wi == 1) {
                    x0 *= NEG_LOG2E; x1 *= NEG_LOG2E; x2 *= NEG_LOG2E; x3 *= NEG_LOG2E;
                } else if (wi == 3) {
                    x0 += bias4[mt].x; x1 += bias4[mt].y;
                    x2 += bias4[mt].z; x3 += bias4[mt].w;
                }
                uint2 st;
                st.x = ((u32)f2bf(x1) << 16) | f2bf(x0);
                st.y = ((u32)f2bf(x3) << 16) | f2bf(x2);
                size_t nb = (size_t)node * 256;
                if      (wi == 0) *(uint2*)(KS + nb + chb) = st;
                else if (wi == 3) *(uint2*)(KS + nb + 128 + chb) = st;
                else if (wi == 1) *(uint2*)(QV + nb + 2 * chb) = st;
                else              *(uint2*)(QV + nb + 2 * chb + 4) = st;
            }
        }
    }
}

// ---------------------------------------------------------------------------
// CSR gather-reduce edge phase: one wave per dst node, TWO edges per load
// (half-wave per edge, lane covers 4 channels via one dwordx4 row load).
// MLP=2 (best measured config). MODE 0: relu row -> Xout. MODE 1: fused gemv3.
template<int MODE>
__global__ __launch_bounds__(256)
void edge_csr2(const int* __restrict__ rowp, const int* __restrict__ ssrc,
               const u16* __restrict__ KS, const u16* __restrict__ QV,
               u16* __restrict__ Xout,
               const float* __restrict__ Wk3, const float* __restrict__ Wq3,
               const float* __restrict__ Wv3, const float* __restrict__ Ws3,
               const float* __restrict__ b3,
               float* __restrict__ k3, float2* __restrict__ qv3,
               float* __restrict__ s3, int N)
{
    const int lane = threadIdx.x & 63;
    const int half = lane >> 5;
    const int t    = lane & 31;       // channel group: channels 4t..4t+3
    int gw = blockIdx.x * (blockDim.x >> 6) + (threadIdx.x >> 6);
    int nw = gridDim.x * (blockDim.x >> 6);

    float4 wk4, wq4, wv4, ws4;
    float bias3 = 0.0f;
    if (MODE == 1) {
        wk4 = *(const float4*)(Wk3 + 4 * t);
        wq4 = *(const float4*)(Wq3 + 4 * t);
        wv4 = *(const float4*)(Wv3 + 4 * t);
        ws4 = *(const float4*)(Ws3 + 4 * t);
        bias3 = b3[0];
    }

#define LOAD2(S0, S1) (*((const uint4*)(QV + (size_t)(half ? (S1) : (S0)) * 256) + t))
#define COMP(QVv, A0, A1, A2, A3)                                             \
    {                                                                         \
        float q0_, q1_, q2_, q3_, v0_, v1_, v2_, v3_;                         \
        bfu2((QVv).x, q0_, q1_); bfu2((QVv).y, q2_, q3_);                     \
        bfu2((QVv).z, v0_, v1_); bfu2((QVv).w, v2_, v3_);                     \
        A0 += gate(k0 + q0_) * v0_;  A1 += gate(k1 + q1_) * v1_;              \
        A2 += gate(k2 + q2_) * v2_;  A3 += gate(k3v + q3_) * v3_;             \
    }

    for (int d = gw; d < N; d += nw) {
        int beg = rowp[d], end = rowp[d + 1];
        uint2 kk = *(const uint2*)(KS + (size_t)d * 256 + t * 4);
        float k0, k1, k2, k3v;
        bfu2(kk.x, k0, k1); bfu2(kk.y, k2, k3v);
        float a0 = 0.f, a1 = 0.f, a2 = 0.f, a3 = 0.f;
        float e0 = 0.f, e1 = 0.f, e2 = 0.f, e3 = 0.f;

        for (int base = beg; base < end; base += 64) {
            int e = base + lane;
            int sv = (e < end) ? ssrc[e] : 0;
            int m = end - base; if (m > 64) m = 64;
            int j = 0;
            for (; j + 4 <= m; j += 4) {
                int sa0 = __builtin_amdgcn_readlane(sv, j);
                int sa1 = __builtin_amdgcn_readlane(sv, j + 1);
                int sb0 = __builtin_amdgcn_readlane(sv, j + 2);
                int sb1 = __builtin_amdgcn_readlane(sv, j + 3);
                uint4 qA = LOAD2(sa0, sa1);
                uint4 qB = LOAD2(sb0, sb1);
                COMP(qA, a0, a1, a2, a3);
                COMP(qB, e0, e1, e2, e3);
            }
            if (j + 2 <= m) {
                int s0 = __builtin_amdgcn_readlane(sv, j);
                int s1 = __builtin_amdgcn_readlane(sv, j + 1);
                uint4 qA = LOAD2(s0, s1);
                COMP(qA, a0, a1, a2, a3);
                j += 2;
            }
            if (j < m) {  // single odd edge: only half 0 accumulates
                int s0i = __builtin_amdgcn_readlane(sv, j);
                uint4 qv_ = *((const uint4*)(QV + (size_t)s0i * 256) + t);
                float q0_, q1_, q2_, q3_, v0_, v1_, v2_, v3_;
                bfu2(qv_.x, q0_, q1_); bfu2(qv_.y, q2_, q3_);
                bfu2(qv_.z, v0_, v1_); bfu2(qv_.w, v2_, v3_);
                if (half == 0) {
                    a0 += gate(k0 + q0_) * v0_;  a1 += gate(k1 + q1_) * v1_;
                    a2 += gate(k2 + q2_) * v2_;  a3 += gate(k3v + q3_) * v3_;
                }
            }
        }
#undef LOAD2
#undef COMP

        a0 += e0; a1 += e1; a2 += e2; a3 += e3;
        a0 += __shfl_xor(a0, 32);
        a1 += __shfl_xor(a1, 32);
        a2 += __shfl_xor(a2, 32);
        a3 += __shfl_xor(a3, 32);

        uint2 ss = *(const uint2*)(KS + (size_t)d * 256 + 128 + t * 4);
        float s0f, s1f, s2f, s3f;
        bfu2(ss.x, s0f, s1f); bfu2(ss.y, s2f, s3f);
        float r0 = fmaxf(s0f + a0, 0.f);
        float r1 = fmaxf(s1f + a1, 0.f);
        float r2 = fmaxf(s2f + a2, 0.f);
        float r3 = fmaxf(s3f + a3, 0.f);

        if (MODE == 0) {
            if (half == 0) {
                uint2 st;
                st.x = ((u32)f2bf(r1) << 16) | f2bf(r0);
                st.y = ((u32)f2bf(r3) << 16) | f2bf(r2);
                *(uint2*)(Xout + (size_t)d * 128 + t * 4) = st;
            }
        } else {
            float pk = r0 * wk4.x + r1 * wk4.y + r2 * wk4.z + r3 * wk4.w;
            float pq = r0 * wq4.x + r1 * wq4.y + r2 * wq4.z + r3 * wq4.w;
            float pv = r0 * wv4.x + r1 * wv4.y + r2 * wv4.z + r3 * wv4.w;
            float ps = r0 * ws4.x + r1 * ws4.y + r2 * ws4.z + r3 * ws4.w;
            for (int off = 1; off < 32; off <<= 1) {
                pk += __shfl_xor(pk, off);
                pq += __shfl_xor(pq, off);
                pv += __shfl_xor(pv, off);
                ps += __shfl_xor(ps, off);
            }
            if (lane == 0) {
                k3[d]  = NEG_LOG2E * pk;
                qv3[d] = make_float2(NEG_LOG2E * pq, pv);
                s3[d]  = ps + bias3;
            }
        }
    }
}

// ---------------------------------------------------------------------------
// CSR edge phase, Dout=1: wave per node; qv3 packed float2 (one 8B gather).
__global__ __launch_bounds__(256)
void edge3_csr(const int* __restrict__ rowp, const int* __restrict__ ssrc,
               const float* __restrict__ k3, const float2* __restrict__ qv3,
               const float* __restrict__ s3, float* __restrict__ outp, int N)
{
    int lane = threadIdx.x & 63;
    int gw = blockIdx.x * (blockDim.x >> 6) + (threadIdx.x >> 6);
    int nw = gridDim.x * (blockDim.x >> 6);
    for (int d = gw; d < N; d += nw) {
        int beg = rowp[d], end = rowp[d + 1];
        float kd = k3[d];
        float sum = 0.0f;
        for (int e = beg + lane; e < end; e += 64) {
            float2 qv = qv3[ssrc[e]];
            sum += gate(kd + qv.x) * qv.y;
        }
        for (int off = 32; off > 0; off >>= 1) sum += __shfl_xor(sum, off);
        if (lane == 0) outp[d] = s3[d] + sum;
    }
}

// ---------------------------------------------------------------------------
extern "C" void kernel_launch(void* const* d_in, const int* in_sizes, int n_in,
                              void* d_out, int out_size, void* d_ws, size_t ws_size,
                              hipStream_t stream)
{
    const float* x0 = (const float*)d_in[0];
    const int*   ei = (const int*)d_in[1];
    const int    N  = in_sizes[0] / 128;   // 100000
    const int    E  = in_sizes[1] / 2;     // 1600000
    const int* src = ei;
    const int* dst = ei + E;

    char* ws = (char*)d_ws;
    size_t off = 0;
    auto carve = [&](size_t bytes) { void* p = ws + off; off += (bytes + 255) & ~(size_t)255; return p; };
    u16*    Wt   = (u16*)carve((size_t)8 * 16384 * sizeof(u16));
    u16*    bufX = (u16*)carve((size_t)N * 128 * sizeof(u16));
    u16*    KS   = (u16*)carve((size_t)N * 256 * sizeof(u16));
    u16*    QV   = (u16*)carve((size_t)N * 256 * sizeof(u16));
    int*    ssrc = (int*)carve((size_t)E * sizeof(int));
    int*    rowp = (int*)carve((size_t)(N + 1) * sizeof(int));
    int*    deg  = (int*)carve((size_t)N * sizeof(int));
    int*    cur  = (int*)carve((size_t)N * sizeof(int));
    int*    part = (int*)carve((size_t)128 * sizeof(int));
    float*  k3   = (float*)carve((size_t)N * sizeof(float));
    float2* qv3  = (float2*)carve((size_t)N * sizeof(float2));
    float*  s3   = (float*)carve((size_t)N * sizeof(float));

    // --- prep: weight transpose + deg zero (one kernel) ---
    P8 wp;
    wp.p[0] = (const float*)d_in[2];  wp.p[1] = (const float*)d_in[3];
    wp.p[2] = (const float*)d_in[4];  wp.p[3] = (const float*)d_in[5];
    wp.p[4] = (const float*)d_in[7];  wp.p[5] = (const float*)d_in[8];
    wp.p[6] = (const float*)d_in[9];  wp.p[7] = (const float*)d_in[10];
    prep_k<<<64, 256, 0, stream>>>(wp, Wt, deg, N);

    // --- CSR build ---
    hist_k<<<2048, 256, 0, stream>>>(dst, deg, E);
    int nb = (N + 1023) / 1024;  // 98
    scan_part_k<<<nb, 256, 0, stream>>>(deg, part, N);
    scan_tops_k<<<1, 128, 0, stream>>>(part, nb);
    scan_emit_k<<<nb, 256, 0, stream>>>(deg, part, rowp, cur, N, E);
    scatter_k<<<2048, 256, 0, stream>>>(src, dst, cur, ssrc, E);

    int gb = (N + 127) / 128;

    // layer 1 (reads fp32 x directly, casts in staging)
    gemm_kqvs<1><<<gb, 256, 0, stream>>>(x0, Wt, (const float*)d_in[6], KS, QV, N);
    edge_csr2<0><<<4096, 256, 0, stream>>>(rowp, ssrc, KS, QV, bufX,
        nullptr, nullptr, nullptr, nullptr, nullptr, nullptr, nullptr, nullptr, N);
    // layer 2 (+ fused layer-3 GEMV)
    gemm_kqvs<0><<<gb, 256, 0, stream>>>(bufX, Wt + 4 * 16384, (const float*)d_in[11], KS, QV, N);
    edge_csr2<1><<<4096, 256, 0, stream>>>(rowp, ssrc, KS, QV, nullptr,
        (const float*)d_in[12], (const float*)d_in[13], (const float*)d_in[14],
        (const float*)d_in[15], (const float*)d_in[16],
        k3, qv3, s3, N);
    // layer 3 edge pass -> d_out
    edge3_csr<<<2048, 256, 0, stream>>>(rowp, ssrc, k3, qv3, s3, (float*)d_out, N);
}

// Round 9
// 554.551 us; speedup vs baseline: 1.3918x; 1.2594x over previous
//
#include <hip/hip_runtime.h>
#include <hip/hip_bf16.h>
#include <cstdint>

typedef unsigned short u16;
typedef unsigned int   u32;
typedef __attribute__((ext_vector_type(8))) short bf16x8;  // 8 bf16 = 4 VGPRs
typedef __attribute__((ext_vector_type(4))) float f32x4;

#define NEG_LOG2E -1.44269504088896f

__device__ __forceinline__ float bf2f(u16 u) {
    union { u32 i; float f; } c; c.i = ((u32)u) << 16; return c.f;
}
__device__ __forceinline__ u16 f2bf(float f) {
    union { float f; u32 i; } c; c.f = f;
    u32 x = c.i;
    return (u16)((x + 0x7fffu + ((x >> 16) & 1u)) >> 16);  // RNE
}
// unpack packed bf16 pair (2 VALU: lshl + and)
__device__ __forceinline__ void bfu2(u32 p, float& lo, float& hi) {
    union { u32 i; float f; } a, b;
    a.i = p << 16; b.i = p & 0xffff0000u;
    lo = a.f; hi = b.f;
}
// gate = sigmoid(k+q) given zt = -log2e*(k+q):  rcp(1 + exp2(zt))
__device__ __forceinline__ float gate(float zt) {
    return __builtin_amdgcn_rcpf(1.0f + __builtin_amdgcn_exp2f(zt));
}

// ---------------------------------------------------------------------------
// prep: transpose+cast all 8 weight matrices (64 blocks: mat = blk>>3).
struct P8 { const float* p[8]; };
__global__ __launch_bounds__(256)
void prep_k(P8 wsrc, u16* __restrict__ Wt) {
    int t = threadIdx.x;
    int mat = blockIdx.x >> 3, seg = blockIdx.x & 7;
    const float* W = wsrc.p[mat];
    u16* T = Wt + (size_t)mat * 16384;
    for (int p = 0; p < 8; ++p) {
        int idx = seg * 2048 + p * 256 + t;
        int k = idx >> 7, n = idx & 127;
        T[n * 128 + k] = f2bf(W[k * 128 + n]);
    }
}

// ---------------------------------------------------------------------------
// Atomic-free CSR build: two-level bucket sort (NO global atomics anywhere).
//   coarse bucket = dst >> 8  (NBUCK = ceil(N/256) = 391)
//   A-chunk CH = 2048 edges   (NA = ceil(E/2048) = 782)
//   cnt[bucket*NA + blk] histogram -> 3-phase scan -> exact scatter bases.

#define CSR_CH 2048

// A1: per-chunk LDS histogram over coarse buckets
__global__ __launch_bounds__(256)
void sortA_hist(const int* __restrict__ dst, int* __restrict__ cnt,
                int nE, int NA, int nbuck) {
    __shared__ int lh[512];
    int t = threadIdx.x, b = blockIdx.x;
    for (int i = t; i < nbuck; i += 256) lh[i] = 0;
    __syncthreads();
    int i0 = b * CSR_CH, iend = min(i0 + CSR_CH, nE);
    for (int i = i0 + t; i < iend; i += 256) atomicAdd(&lh[dst[i] >> 8], 1);
    __syncthreads();
    for (int i = t; i < nbuck; i += 256) cnt[i * NA + b] = lh[i];
}

// scan phase 1: per-block (1024-elem chunk) total
__global__ __launch_bounds__(256)
void scan_part_k(const int* __restrict__ arr, int* __restrict__ part, int M) {
    __shared__ int wsum[4];
    int t = threadIdx.x, lane = t & 63, wave = t >> 6;
    int i0 = blockIdx.x * 1024 + t * 4;
    int s = 0;
    for (int j = 0; j < 4; ++j) { int i = i0 + j; if (i < M) s += arr[i]; }
    for (int off = 32; off > 0; off >>= 1) s += __shfl_xor(s, off);
    if (lane == 0) wsum[wave] = s;
    __syncthreads();
    if (t == 0) part[blockIdx.x] = wsum[0] + wsum[1] + wsum[2] + wsum[3];
}

// scan phase 2: one block scans <=512 block totals -> exclusive offsets
__global__ __launch_bounds__(512)
void scan_tops512(int* __restrict__ part, int nb) {
    __shared__ int sh[512];
    int t = threadIdx.x;
    int v = (t < nb) ? part[t] : 0;
    sh[t] = v;
    __syncthreads();
    for (int off = 1; off < 512; off <<= 1) {
        int u = (t >= off) ? sh[t - off] : 0;
        __syncthreads();
        sh[t] += u;
        __syncthreads();
    }
    if (t < nb) part[t] = sh[t] - v;  // exclusive
}

// scan phase 3: re-scan chunk locally, add block offset, emit exclusive scan
__global__ __launch_bounds__(256)
void scan_emit_k(const int* __restrict__ arr, const int* __restrict__ part,
                 int* __restrict__ outp, int M, int total) {
    __shared__ int woff[4];
    int t = threadIdx.x, lane = t & 63, wave = t >> 6;
    int i0 = blockIdx.x * 1024 + t * 4;
    int d[4]; int s = 0;
    for (int j = 0; j < 4; ++j) { int i = i0 + j; d[j] = (i < M) ? arr[i] : 0; s += d[j]; }
    int ws = s;
    for (int off = 1; off < 64; off <<= 1) {
        int u = __shfl_up(ws, off);
        if (lane >= off) ws += u;
    }
    if (lane == 63) woff[wave] = ws;
    __syncthreads();
    int base = part[blockIdx.x];
    for (int w = 0; w < wave; ++w) base += woff[w];
    int ex = base + ws - s;
    for (int j = 0; j < 4; ++j) {
        int i = i0 + j;
        if (i < M) outp[i] = ex;
        ex += d[j];
    }
    if (blockIdx.x == 0 && t == 0) outp[M] = total;  // sentinel
}

// A3: coarse scatter via LDS-atomic local ranks; packed key = (dst&255)<<24 | src
__global__ __launch_bounds__(256)
void sortA_scat(const int* __restrict__ src, const int* __restrict__ dst,
                const int* __restrict__ scnt, u32* __restrict__ tkey,
                int nE, int NA, int nbuck) {
    __shared__ int lh[512];
    __shared__ int lbase[512];
    int t = threadIdx.x, b = blockIdx.x;
    for (int i = t; i < nbuck; i += 256) { lh[i] = 0; lbase[i] = scnt[i * NA + b]; }
    __syncthreads();
    int i0 = b * CSR_CH, iend = min(i0 + CSR_CH, nE);
    for (int i = i0 + t; i < iend; i += 256) {
        int d = dst[i], s = src[i];
        int bk = d >> 8;
        int r = atomicAdd(&lh[bk], 1);
        tkey[lbase[bk] + r] = ((u32)(d & 255) << 24) | (u32)s;
    }
}

// B: per-bucket fine grouping. Emits rowp (exact CSR offsets) and ssrc.
__global__ __launch_bounds__(256)
void sortB(const u32* __restrict__ tkey, const int* __restrict__ scnt,
           int* __restrict__ rowp, int* __restrict__ ssrc,
           int NA, int N, int nE) {
    __shared__ int h[256];
    __shared__ int off[256];
    int t = threadIdx.x, b = blockIdx.x;
    int base = scnt[b * NA];
    int endp = scnt[(b + 1) * NA];   // sentinel covers last bucket
    h[t] = 0;
    __syncthreads();
    for (int i = base + t; i < endp; i += 256)
        atomicAdd(&h[tkey[i] >> 24], 1);
    __syncthreads();
    // exclusive scan of h into off (Hillis-Steele)
    int v = h[t];
    off[t] = v;
    __syncthreads();
    for (int d = 1; d < 256; d <<= 1) {
        int u = (t >= d) ? off[t - d] : 0;
        __syncthreads();
        off[t] += u;
        __syncthreads();
    }
    int ex = off[t] - v;
    __syncthreads();
    off[t] = ex;
    h[t] = 0;
    __syncthreads();
    int dglob = b * 256 + t;
    if (dglob < N) rowp[dglob] = base + ex;
    if (b == 0 && t == 0) rowp[N] = nE;
    for (int i = base + t; i < endp; i += 256) {
        u32 k = tkey[i];
        int loc = k >> 24;
        int r = atomicAdd(&h[loc], 1);
        ssrc[base + off[loc] + r] = (int)(k & 0xFFFFFFu);
    }
}

// ---------------------------------------------------------------------------
// Fused GEMM (operand-swapped: A = W^T rows = out-channels, B = X rows = nodes)
//   D[ch][node] -> each lane holds 4 CONSECUTIVE channels of one node
//   KS[node][0..127]   = K~ (canonical)   KS[node][128..255] = S (canonical)
//   QV[node][g*8+0..3] = Q~[4g..4g+3]     QV[node][g*8+4..7] = V[4g..4g+3]
// F32=1: X is fp32, cast to bf16 during LDS staging (layer 1).
#define XS 136  // 128 + 8 pad -> 2-way LDS bank aliasing (free per m136)
template<int F32>
__global__ __launch_bounds__(256, 2)
void gemm_kqvs(const void* __restrict__ Xv, const u16* __restrict__ Wt,
               const float* __restrict__ bias,
               u16* __restrict__ KS, u16* __restrict__ QV, int nrows)
{
    __shared__ u16 xs[128 * XS];
    __shared__ u16 wsl[128 * XS];
    const int tid  = threadIdx.x;
    const int wave = tid >> 6, lane = tid & 63;
    const int quad = lane >> 4, l16 = lane & 15;
    const int r0 = blockIdx.x * 128;

    for (int p = 0; p < 8; ++p) {
        int c = p * 256 + tid;
        int row = c >> 4;
        int col = (c & 15) * 8;
        int gr = r0 + row; if (gr >= nrows) gr = nrows - 1;
        if (F32) {
            const float* sp = (const float*)Xv + (size_t)gr * 128 + col;
            float4 f0 = *(const float4*)(sp);
            float4 f1 = *(const float4*)(sp + 4);
            uint4 st;
            st.x = ((u32)f2bf(f0.y) << 16) | f2bf(f0.x);
            st.y = ((u32)f2bf(f0.w) << 16) | f2bf(f0.z);
            st.z = ((u32)f2bf(f1.y) << 16) | f2bf(f1.x);
            st.w = ((u32)f2bf(f1.w) << 16) | f2bf(f1.z);
            *(uint4*)(&xs[row * XS + col]) = st;
        } else {
            uint4 d = *(const uint4*)((const u16*)Xv + (size_t)gr * 128 + col);
            *(uint4*)(&xs[row * XS + col]) = d;
        }
    }

    for (int wi = 0; wi < 4; ++wi) {
        __syncthreads();
        const u16* Wsrc = Wt + wi * (128 * 128);
        for (int p = 0; p < 8; ++p) {
            int c = p * 256 + tid;
            int row = c >> 4;
            int col = (c & 15) * 8;
            uint4 d = *(const uint4*)(Wsrc + row * 128 + col);
            *(uint4*)(&wsl[row * XS + col]) = d;
        }
        __syncthreads();

        f32x4 acc[2][8];
        for (int mt = 0; mt < 2; ++mt)
            for (int nt = 0; nt < 8; ++nt) acc[mt][nt] = (f32x4)0.0f;

        const int cbase = wave * 32;  // this wave's 32 output channels
        for (int kt = 0; kt < 4; ++kt) {
            bf16x8 a0 = *(const bf16x8*)&wsl[(cbase + l16)      * XS + kt * 32 + quad * 8];
            bf16x8 a1 = *(const bf16x8*)&wsl[(cbase + 16 + l16) * XS + kt * 32 + quad * 8];
            for (int nt = 0; nt < 8; ++nt) {
                bf16x8 b = *(const bf16x8*)&xs[(nt * 16 + l16) * XS + kt * 32 + quad * 8];
                acc[0][nt] = __builtin_amdgcn_mfma_f32_16x16x32_bf16(a0, b, acc[0][nt], 0, 0, 0);
                acc[1][nt] = __builtin_amdgcn_mfma_f32_16x16x32_bf16(a1, b, acc[1][nt], 0, 0, 0);
            }
        }

        float4 bias4[2];
        if (wi == 3) {
            bias4[0] = *(const float4*)(bias + cbase + quad * 4);
            bias4[1] = *(const float4*)(bias + cbase + 16 + quad * 4);
        }
        for (int mt = 0; mt < 2; ++mt) {
            int chb = cbase + mt * 16 + quad * 4;
            for (int nt = 0; nt < 8; ++nt) {
                int node = r0 + nt * 16 + l16;
                if (node >= nrows) continue;
                f32x4 v = acc[mt][nt];
                float x0 = v[0], x1 = v[1], x2 = v[2], x3 = v[3];
                if (wi == 0 || wi == 1) {
                    x0 *= NEG_LOG2E; x1 *= NEG_LOG2E; x2 *= NEG_LOG2E; x3 *= NEG_LOG2E;
                } else if (wi == 3) {
                    x0 += bias4[mt].x; x1 += bias4[mt].y;
                    x2 += bias4[mt].z; x3 += bias4[mt].w;
                }
                uint2 st;
                st.x = ((u32)f2bf(x1) << 16) | f2bf(x0);
                st.y = ((u32)f2bf(x3) << 16) | f2bf(x2);
                size_t nb = (size_t)node * 256;
                if      (wi == 0) *(uint2*)(KS + nb + chb) = st;
                else if (wi == 3) *(uint2*)(KS + nb + 128 + chb) = st;
                else if (wi == 1) *(uint2*)(QV + nb + 2 * chb) = st;
                else              *(uint2*)(QV + nb + 2 * chb + 4) = st;
            }
        }
    }
}

// ---------------------------------------------------------------------------
// CSR gather-reduce edge phase: one wave per dst node, TWO edges per load
// (half-wave per edge, lane covers 4 channels via one dwordx4 row load).
// MLP=2 (best measured config). MODE 0: relu row -> Xout. MODE 1: fused gemv3.
template<int MODE>
__global__ __launch_bounds__(256)
void edge_csr2(const int* __restrict__ rowp, const int* __restrict__ ssrc,
               const u16* __restrict__ KS, const u16* __restrict__ QV,
               u16* __restrict__ Xout,
               const float* __restrict__ Wk3, const float* __restrict__ Wq3,
               const float* __restrict__ Wv3, const float* __restrict__ Ws3,
               const float* __restrict__ b3,
               float* __restrict__ k3, float2* __restrict__ qv3,
               float* __restrict__ s3, int N)
{
    const int lane = threadIdx.x & 63;
    const int half = lane >> 5;
    const int t    = lane & 31;       // channel group: channels 4t..4t+3
    int gw = blockIdx.x * (blockDim.x >> 6) + (threadIdx.x >> 6);
    int nw = gridDim.x * (blockDim.x >> 6);

    float4 wk4, wq4, wv4, ws4;
    float bias3 = 0.0f;
    if (MODE == 1) {
        wk4 = *(const float4*)(Wk3 + 4 * t);
        wq4 = *(const float4*)(Wq3 + 4 * t);
        wv4 = *(const float4*)(Wv3 + 4 * t);
        ws4 = *(const float4*)(Ws3 + 4 * t);
        bias3 = b3[0];
    }

#define LOAD2(S0, S1) (*((const uint4*)(QV + (size_t)(half ? (S1) : (S0)) * 256) + t))
#define COMP(QVv, A0, A1, A2, A3)                                             \
    {                                                                         \
        float q0_, q1_, q2_, q3_, v0_, v1_, v2_, v3_;                         \
        bfu2((QVv).x, q0_, q1_); bfu2((QVv).y, q2_, q3_);                     \
        bfu2((QVv).z, v0_, v1_); bfu2((QVv).w, v2_, v3_);                     \
        A0 += gate(k0 + q0_) * v0_;  A1 += gate(k1 + q1_) * v1_;              \
        A2 += gate(k2 + q2_) * v2_;  A3 += gate(k3v + q3_) * v3_;             \
    }

    for (int d = gw; d < N; d += nw) {
        int beg = rowp[d], end = rowp[d + 1];
        uint2 kk = *(const uint2*)(KS + (size_t)d * 256 + t * 4);
        float k0, k1, k2, k3v;
        bfu2(kk.x, k0, k1); bfu2(kk.y, k2, k3v);
        float a0 = 0.f, a1 = 0.f, a2 = 0.f, a3 = 0.f;
        float e0 = 0.f, e1 = 0.f, e2 = 0.f, e3 = 0.f;

        for (int base = beg; base < end; base += 64) {
            int e = base + lane;
            int sv = (e < end) ? ssrc[e] : 0;
            int m = end - base; if (m > 64) m = 64;
            int j = 0;
            for (; j + 4 <= m; j += 4) {
                int sa0 = __builtin_amdgcn_readlane(sv, j);
                int sa1 = __builtin_amdgcn_readlane(sv, j + 1);
                int sb0 = __builtin_amdgcn_readlane(sv, j + 2);
                int sb1 = __builtin_amdgcn_readlane(sv, j + 3);
                uint4 qA = LOAD2(sa0, sa1);
                uint4 qB = LOAD2(sb0, sb1);
                COMP(qA, a0, a1, a2, a3);
                COMP(qB, e0, e1, e2, e3);
            }
            if (j + 2 <= m) {
                int s0 = __builtin_amdgcn_readlane(sv, j);
                int s1 = __builtin_amdgcn_readlane(sv, j + 1);
                uint4 qA = LOAD2(s0, s1);
                COMP(qA, a0, a1, a2, a3);
                j += 2;
            }
            if (j < m) {  // single odd edge: only half 0 accumulates
                int s0i = __builtin_amdgcn_readlane(sv, j);
                uint4 qv_ = *((const uint4*)(QV + (size_t)s0i * 256) + t);
                float q0_, q1_, q2_, q3_, v0_, v1_, v2_, v3_;
                bfu2(qv_.x, q0_, q1_); bfu2(qv_.y, q2_, q3_);
                bfu2(qv_.z, v0_, v1_); bfu2(qv_.w, v2_, v3_);
                if (half == 0) {
                    a0 += gate(k0 + q0_) * v0_;  a1 += gate(k1 + q1_) * v1_;
                    a2 += gate(k2 + q2_) * v2_;  a3 += gate(k3v + q3_) * v3_;
                }
            }
        }
#undef LOAD2
#undef COMP

        a0 += e0; a1 += e1; a2 += e2; a3 += e3;
        a0 += __shfl_xor(a0, 32);
        a1 += __shfl_xor(a1, 32);
        a2 += __shfl_xor(a2, 32);
        a3 += __shfl_xor(a3, 32);

        uint2 ss = *(const uint2*)(KS + (size_t)d * 256 + 128 + t * 4);
        float s0f, s1f, s2f, s3f;
        bfu2(ss.x, s0f, s1f); bfu2(ss.y, s2f, s3f);
        float r0 = fmaxf(s0f + a0, 0.f);
        float r1 = fmaxf(s1f + a1, 0.f);
        float r2 = fmaxf(s2f + a2, 0.f);
        float r3 = fmaxf(s3f + a3, 0.f);

        if (MODE == 0) {
            if (half == 0) {
                uint2 st;
                st.x = ((u32)f2bf(r1) << 16) | f2bf(r0);
                st.y = ((u32)f2bf(r3) << 16) | f2bf(r2);
                *(uint2*)(Xout + (size_t)d * 128 + t * 4) = st;
            }
        } else {
            float pk = r0 * wk4.x + r1 * wk4.y + r2 * wk4.z + r3 * wk4.w;
            float pq = r0 * wq4.x + r1 * wq4.y + r2 * wq4.z + r3 * wq4.w;
            float pv = r0 * wv4.x + r1 * wv4.y + r2 * wv4.z + r3 * wv4.w;
            float ps = r0 * ws4.x + r1 * ws4.y + r2 * ws4.z + r3 * ws4.w;
            for (int off = 1; off < 32; off <<= 1) {
                pk += __shfl_xor(pk, off);
                pq += __shfl_xor(pq, off);
                pv += __shfl_xor(pv, off);
                ps += __shfl_xor(ps, off);
            }
            if (lane == 0) {
                k3[d]  = NEG_LOG2E * pk;
                qv3[d] = make_float2(NEG_LOG2E * pq, pv);
                s3[d]  = ps + bias3;
            }
        }
    }
}

// ---------------------------------------------------------------------------
// CSR edge phase, Dout=1: wave per node; qv3 packed float2 (one 8B gather).
__global__ __launch_bounds__(256)
void edge3_csr(const int* __restrict__ rowp, const int* __restrict__ ssrc,
               const float* __restrict__ k3, const float2* __restrict__ qv3,
               const float* __restrict__ s3, float* __restrict__ outp, int N)
{
    int lane = threadIdx.x & 63;
    int gw = blockIdx.x * (blockDim.x >> 6) + (threadIdx.x >> 6);
    int nw = gridDim.x * (blockDim.x >> 6);
    for (int d = gw; d < N; d += nw) {
        int beg = rowp[d], end = rowp[d + 1];
        float kd = k3[d];
        float sum = 0.0f;
        for (int e = beg + lane; e < end; e += 64) {
            float2 qv = qv3[ssrc[e]];
            sum += gate(kd + qv.x) * qv.y;
        }
        for (int off = 32; off > 0; off >>= 1) sum += __shfl_xor(sum, off);
        if (lane == 0) outp[d] = s3[d] + sum;
    }
}

// ---------------------------------------------------------------------------
extern "C" void kernel_launch(void* const* d_in, const int* in_sizes, int n_in,
                              void* d_out, int out_size, void* d_ws, size_t ws_size,
                              hipStream_t stream)
{
    const float* x0 = (const float*)d_in[0];
    const int*   ei = (const int*)d_in[1];
    const int    N  = in_sizes[0] / 128;   // 100000
    const int    E  = in_sizes[1] / 2;     // 1600000
    const int* src = ei;
    const int* dst = ei + E;

    const int NBUCK = (N + 255) >> 8;              // 391
    const int NA    = (E + CSR_CH - 1) / CSR_CH;   // 782
    const int M     = NBUCK * NA;                  // 305,762
    const int nparts = (M + 1023) / 1024;          // 299

    char* ws = (char*)d_ws;
    size_t off = 0;
    auto carve = [&](size_t bytes) { void* p = ws + off; off += (bytes + 255) & ~(size_t)255; return p; };
    u16*    Wt   = (u16*)carve((size_t)8 * 16384 * sizeof(u16));
    u16*    bufX = (u16*)carve((size_t)N * 128 * sizeof(u16));
    u16*    KS   = (u16*)carve((size_t)N * 256 * sizeof(u16));
    u16*    QV   = (u16*)carve((size_t)N * 256 * sizeof(u16));
    int*    ssrc = (int*)carve((size_t)E * sizeof(int));
    u32*    tkey = (u32*)carve((size_t)E * sizeof(u32));
    int*    rowp = (int*)carve((size_t)(N + 1) * sizeof(int));
    int*    cnt  = (int*)carve((size_t)M * sizeof(int));
    int*    scnt = (int*)carve((size_t)(M + 1) * sizeof(int));
    int*    part = (int*)carve((size_t)512 * sizeof(int));
    float*  k3   = (float*)carve((size_t)N * sizeof(float));
    float2* qv3  = (float2*)carve((size_t)N * sizeof(float2));
    float*  s3   = (float*)carve((size_t)N * sizeof(float));

    // --- prep: weight transpose ---
    P8 wp;
    wp.p[0] = (const float*)d_in[2];  wp.p[1] = (const float*)d_in[3];
    wp.p[2] = (const float*)d_in[4];  wp.p[3] = (const float*)d_in[5];
    wp.p[4] = (const float*)d_in[7];  wp.p[5] = (const float*)d_in[8];
    wp.p[6] = (const float*)d_in[9];  wp.p[7] = (const float*)d_in[10];
    prep_k<<<64, 256, 0, stream>>>(wp, Wt);

    // --- atomic-free CSR build ---
    sortA_hist<<<NA, 256, 0, stream>>>(dst, cnt, E, NA, NBUCK);
    scan_part_k<<<nparts, 256, 0, stream>>>(cnt, part, M);
    scan_tops512<<<1, 512, 0, stream>>>(part, nparts);
    scan_emit_k<<<nparts, 256, 0, stream>>>(cnt, part, scnt, M, E);
    sortA_scat<<<NA, 256, 0, stream>>>(src, dst, scnt, tkey, E, NA, NBUCK);
    sortB<<<NBUCK, 256, 0, stream>>>(tkey, scnt, rowp, ssrc, NA, N, E);

    int gb = (N + 127) / 128;

    // layer 1 (reads fp32 x directly, casts in staging)
    gemm_kqvs<1><<<gb, 256, 0, stream>>>(x0, Wt, (const float*)d_in[6], KS, QV, N);
    edge_csr2<0><<<4096, 256, 0, stream>>>(rowp, ssrc, KS, QV, bufX,
        nullptr, nullptr, nullptr, nullptr, nullptr, nullptr, nullptr, nullptr, N);
    // layer 2 (+ fused layer-3 GEMV)
    gemm_kqvs<0><<<gb, 256, 0, stream>>>(bufX, Wt + 4 * 16384, (const float*)d_in[11], KS, QV, N);
    edge_csr2<1><<<4096, 256, 0, stream>>>(rowp, ssrc, KS, QV, nullptr,
        (const float*)d_in[12], (const float*)d_in[13], (const float*)d_in[14],
        (const float*)d_in[15], (const float*)d_in[16],
        k3, qv3, s3, N);
    // layer 3 edge pass -> d_out
    edge3_csr<<<2048, 256, 0, stream>>>(rowp, ssrc, k3, qv3, s3, (float*)d_out, N);
}

// Round 10
// 541.422 us; speedup vs baseline: 1.4255x; 1.0242x over previous
//
#include <hip/hip_runtime.h>
#include <hip/hip_bf16.h>
#include <cstdint>

typedef unsigned short u16;
typedef unsigned int   u32;
typedef __attribute__((ext_vector_type(8))) short bf16x8;  // 8 bf16 = 4 VGPRs
typedef __attribute__((ext_vector_type(4))) float f32x4;

#define NEG_LOG2E -1.44269504088896f

__device__ __forceinline__ float bf2f(u16 u) {
    union { u32 i; float f; } c; c.i = ((u32)u) << 16; return c.f;
}
__device__ __forceinline__ u16 f2bf(float f) {
    union { float f; u32 i; } c; c.f = f;
    u32 x = c.i;
    return (u16)((x + 0x7fffu + ((x >> 16) & 1u)) >> 16);  // RNE
}
// unpack packed bf16 pair (2 VALU: lshl + and)
__device__ __forceinline__ void bfu2(u32 p, float& lo, float& hi) {
    union { u32 i; float f; } a, b;
    a.i = p << 16; b.i = p & 0xffff0000u;
    lo = a.f; hi = b.f;
}
// gate = sigmoid(k+q) given zt = -log2e*(k+q):  rcp(1 + exp2(zt))
__device__ __forceinline__ float gate(float zt) {
    return __builtin_amdgcn_rcpf(1.0f + __builtin_amdgcn_exp2f(zt));
}

#define CSR_CH 2048
#define XS 136  // 128 + 8 pad -> 2-way LDS bank aliasing (free per m136)

// ---------------------------------------------------------------------------
// Launch 1: prep (weight transpose+cast, 64 blocks) + sortA_hist (NA blocks)
struct P8 { const float* p[8]; };
__global__ __launch_bounds__(256)
void prep_hist_k(P8 wsrc, u16* __restrict__ Wt,
                 const int* __restrict__ dst, int* __restrict__ cnt,
                 int nE, int NA, int nbuck) {
    __shared__ int lh[512];
    int t = threadIdx.x;
    if (blockIdx.x < 64) {
        int mat = blockIdx.x >> 3, seg = blockIdx.x & 7;
        const float* W = wsrc.p[mat];
        u16* T = Wt + (size_t)mat * 16384;
        for (int p = 0; p < 8; ++p) {
            int idx = seg * 2048 + p * 256 + t;
            int k = idx >> 7, n = idx & 127;
            T[n * 128 + k] = f2bf(W[k * 128 + n]);
        }
    } else {
        int b = blockIdx.x - 64;
        for (int i = t; i < nbuck; i += 256) lh[i] = 0;
        __syncthreads();
        int i0 = b * CSR_CH, iend = min(i0 + CSR_CH, nE);
        for (int i = i0 + t; i < iend; i += 256) atomicAdd(&lh[dst[i] >> 8], 1);
        __syncthreads();
        for (int i = t; i < nbuck; i += 256) cnt[i * NA + b] = lh[i];
    }
}

// ---------------------------------------------------------------------------
// scan phase 1: per-block (1024-elem chunk) total
__global__ __launch_bounds__(256)
void scan_part_k(const int* __restrict__ arr, int* __restrict__ part, int M) {
    __shared__ int wsum[4];
    int t = threadIdx.x, lane = t & 63, wave = t >> 6;
    int i0 = blockIdx.x * 1024 + t * 4;
    int s = 0;
    for (int j = 0; j < 4; ++j) { int i = i0 + j; if (i < M) s += arr[i]; }
    for (int off = 32; off > 0; off >>= 1) s += __shfl_xor(s, off);
    if (lane == 0) wsum[wave] = s;
    __syncthreads();
    if (t == 0) part[blockIdx.x] = wsum[0] + wsum[1] + wsum[2] + wsum[3];
}

// scan phase 2+3 merged: every block scans the (<=512) partials in LDS
// (redundant, ~1KB), takes its own exclusive base, then emits its chunk.
__global__ __launch_bounds__(256)
void scan_emit2_k(const int* __restrict__ arr, const int* __restrict__ part,
                  int* __restrict__ outp, int M, int total, int nparts) {
    __shared__ int sh[512];
    __shared__ int woff[4];
    int t = threadIdx.x, lane = t & 63, wave = t >> 6;
    sh[t]       = (t < nparts)       ? part[t]       : 0;
    sh[t + 256] = (t + 256 < nparts) ? part[t + 256] : 0;
    __syncthreads();
    for (int off = 1; off < 512; off <<= 1) {
        int u0 = (t >= off)       ? sh[t - off]       : 0;
        int u1 = (t + 256 >= off) ? sh[t + 256 - off] : 0;
        __syncthreads();
        sh[t] += u0; sh[t + 256] += u1;
        __syncthreads();
    }
    int base = (blockIdx.x == 0) ? 0 : sh[blockIdx.x - 1];
    __syncthreads();

    int i0 = blockIdx.x * 1024 + t * 4;
    int d[4]; int s = 0;
    for (int j = 0; j < 4; ++j) { int i = i0 + j; d[j] = (i < M) ? arr[i] : 0; s += d[j]; }
    int ws = s;
    for (int off = 1; off < 64; off <<= 1) {
        int u = __shfl_up(ws, off);
        if (lane >= off) ws += u;
    }
    if (lane == 63) woff[wave] = ws;
    __syncthreads();
    for (int w = 0; w < wave; ++w) base += woff[w];
    int ex = base + ws - s;
    for (int j = 0; j < 4; ++j) {
        int i = i0 + j;
        if (i < M) outp[i] = ex;
        ex += d[j];
    }
    if (blockIdx.x == 0 && t == 0) outp[M] = total;  // sentinel
}

// A3: coarse scatter via LDS-atomic local ranks; packed key = (dst&255)<<24 | src
__global__ __launch_bounds__(256)
void sortA_scat(const int* __restrict__ src, const int* __restrict__ dst,
                const int* __restrict__ scnt, u32* __restrict__ tkey,
                int nE, int NA, int nbuck) {
    __shared__ int lh[512];
    __shared__ int lbase[512];
    int t = threadIdx.x, b = blockIdx.x;
    for (int i = t; i < nbuck; i += 256) { lh[i] = 0; lbase[i] = scnt[i * NA + b]; }
    __syncthreads();
    int i0 = b * CSR_CH, iend = min(i0 + CSR_CH, nE);
    for (int i = i0 + t; i < iend; i += 256) {
        int d = dst[i], s = src[i];
        int bk = d >> 8;
        int r = atomicAdd(&lh[bk], 1);
        tkey[lbase[bk] + r] = ((u32)(d & 255) << 24) | (u32)s;
    }
}

// ---------------------------------------------------------------------------
// sortB body: per-bucket fine grouping (uses caller-provided LDS)
__device__ __forceinline__
void sortB_body(const u32* __restrict__ tkey, const int* __restrict__ scnt,
                int* __restrict__ rowp, int* __restrict__ ssrc,
                int NA, int N, int nE, int b, int* h, int* offv) {
    int t = threadIdx.x;
    int base = scnt[b * NA];
    int endp = scnt[(b + 1) * NA];   // sentinel covers last bucket
    h[t] = 0;
    __syncthreads();
    for (int i = base + t; i < endp; i += 256)
        atomicAdd(&h[tkey[i] >> 24], 1);
    __syncthreads();
    int v = h[t];
    offv[t] = v;
    __syncthreads();
    for (int d = 1; d < 256; d <<= 1) {
        int u = (t >= d) ? offv[t - d] : 0;
        __syncthreads();
        offv[t] += u;
        __syncthreads();
    }
    int ex = offv[t] - v;
    __syncthreads();
    offv[t] = ex;
    h[t] = 0;
    __syncthreads();
    int dglob = b * 256 + t;
    if (dglob < N) rowp[dglob] = base + ex;
    if (b == 0 && t == 0) rowp[N] = nE;
    for (int i = base + t; i < endp; i += 256) {
        u32 k = tkey[i];
        int loc = k >> 24;
        int r = atomicAdd(&h[loc], 1);
        ssrc[base + offv[loc] + r] = (int)(k & 0xFFFFFFu);
    }
}

// ---------------------------------------------------------------------------
// GEMM body (operand-swapped). Uses caller-provided LDS (xs, wsl).
template<int F32>
__device__ __forceinline__
void gemm_body(int bid, u16* xs, u16* wsl,
               const void* __restrict__ Xv, const u16* __restrict__ Wt,
               const float* __restrict__ bias,
               u16* __restrict__ KS, u16* __restrict__ QV, int nrows)
{
    const int tid  = threadIdx.x;
    const int wave = tid >> 6, lane = tid & 63;
    const int quad = lane >> 4, l16 = lane & 15;
    const int r0 = bid * 128;

    for (int p = 0; p < 8; ++p) {
        int c = p * 256 + tid;
        int row = c >> 4;
        int col = (c & 15) * 8;
        int gr = r0 + row; if (gr >= nrows) gr = nrows - 1;
        if (F32) {
            const float* sp = (const float*)Xv + (size_t)gr * 128 + col;
            float4 f0 = *(const float4*)(sp);
            float4 f1 = *(const float4*)(sp + 4);
            uint4 st;
            st.x = ((u32)f2bf(f0.y) << 16) | f2bf(f0.x);
            st.y = ((u32)f2bf(f0.w) << 16) | f2bf(f0.z);
            st.z = ((u32)f2bf(f1.y) << 16) | f2bf(f1.x);
            st.w = ((u32)f2bf(f1.w) << 16) | f2bf(f1.z);
            *(uint4*)(&xs[row * XS + col]) = st;
        } else {
            uint4 d = *(const uint4*)((const u16*)Xv + (size_t)gr * 128 + col);
            *(uint4*)(&xs[row * XS + col]) = d;
        }
    }

    for (int wi = 0; wi < 4; ++wi) {
        __syncthreads();
        const u16* Wsrc = Wt + wi * (128 * 128);
        for (int p = 0; p < 8; ++p) {
            int c = p * 256 + tid;
            int row = c >> 4;
            int col = (c & 15) * 8;
            uint4 d = *(const uint4*)(Wsrc + row * 128 + col);
            *(uint4*)(&wsl[row * XS + col]) = d;
        }
        __syncthreads();

        f32x4 acc[2][8];
        for (int mt = 0; mt < 2; ++mt)
            for (int nt = 0; nt < 8; ++nt) acc[mt][nt] = (f32x4)0.0f;

        const int cbase = wave * 32;  // this wave's 32 output channels
        for (int kt = 0; kt < 4; ++kt) {
            bf16x8 a0 = *(const bf16x8*)&wsl[(cbase + l16)      * XS + kt * 32 + quad * 8];
            bf16x8 a1 = *(const bf16x8*)&wsl[(cbase + 16 + l16) * XS + kt * 32 + quad * 8];
            for (int nt = 0; nt < 8; ++nt) {
                bf16x8 b = *(const bf16x8*)&xs[(nt * 16 + l16) * XS + kt * 32 + quad * 8];
                acc[0][nt] = __builtin_amdgcn_mfma_f32_16x16x32_bf16(a0, b, acc[0][nt], 0, 0, 0);
                acc[1][nt] = __builtin_amdgcn_mfma_f32_16x16x32_bf16(a1, b, acc[1][nt], 0, 0, 0);
            }
        }

        float4 bias4[2];
        if (wi == 3) {
            bias4[0] = *(const float4*)(bias + cbase + quad * 4);
            bias4[1] = *(const float4*)(bias + cbase + 16 + quad * 4);
        }
        for (int mt = 0; mt < 2; ++mt) {
            int chb = cbase + mt * 16 + quad * 4;
            for (int nt = 0; nt < 8; ++nt) {
                int node = r0 + nt * 16 + l16;
                if (node >= nrows) continue;
                f32x4 v = acc[mt][nt];
                float x0 = v[0], x1 = v[1], x2 = v[2], x3 = v[3];
                if (wi == 0 || wi == 1) {
                    x0 *= NEG_LOG2E; x1 *= NEG_LOG2E; x2 *= NEG_LOG2E; x3 *= NEG_LOG2E;
                } else if (wi == 3) {
                    x0 += bias4[mt].x; x1 += bias4[mt].y;
                    x2 += bias4[mt].z; x3 += bias4[mt].w;
                }
                uint2 st;
                st.x = ((u32)f2bf(x1) << 16) | f2bf(x0);
                st.y = ((u32)f2bf(x3) << 16) | f2bf(x2);
                size_t nb = (size_t)node * 256;
                if      (wi == 0) *(uint2*)(KS + nb + chb) = st;
                else if (wi == 3) *(uint2*)(KS + nb + 128 + chb) = st;
                else if (wi == 1) *(uint2*)(QV + nb + 2 * chb) = st;
                else              *(uint2*)(QV + nb + 2 * chb + 4) = st;
            }
        }
    }
}

// Launch 5: sortB (blocks < nbuck) + layer-1 GEMM (remaining blocks)
__global__ __launch_bounds__(256, 2)
void sortB_gemm1(const u32* __restrict__ tkey, const int* __restrict__ scnt,
                 int* __restrict__ rowp, int* __restrict__ ssrc,
                 int NA, int N, int nE, int nbuck,
                 const float* __restrict__ x0, const u16* __restrict__ Wt,
                 const float* __restrict__ bias,
                 u16* __restrict__ KS, u16* __restrict__ QV)
{
    __shared__ u16 xs[128 * XS];
    __shared__ u16 wsl[128 * XS];
    if ((int)blockIdx.x < nbuck) {
        int* h = (int*)xs;
        int* offv = h + 256;
        sortB_body(tkey, scnt, rowp, ssrc, NA, N, nE, blockIdx.x, h, offv);
    } else {
        gemm_body<1>(blockIdx.x - nbuck, xs, wsl, x0, Wt, bias, KS, QV, N);
    }
}

// Layer-2 standalone GEMM
__global__ __launch_bounds__(256, 2)
void gemm_l2(const u16* __restrict__ X, const u16* __restrict__ Wt,
             const float* __restrict__ bias,
             u16* __restrict__ KS, u16* __restrict__ QV, int nrows)
{
    __shared__ u16 xs[128 * XS];
    __shared__ u16 wsl[128 * XS];
    gemm_body<0>(blockIdx.x, xs, wsl, X, Wt, bias, KS, QV, nrows);
}

// ---------------------------------------------------------------------------
// CSR gather-reduce edge phase: one wave per dst node, TWO edges per load
// (half-wave per edge, lane covers 4 channels via one dwordx4 row load).
// MLP=2 (best measured config). MODE 0: relu row -> Xout. MODE 1: fused gemv3.
template<int MODE>
__global__ __launch_bounds__(256)
void edge_csr2(const int* __restrict__ rowp, const int* __restrict__ ssrc,
               const u16* __restrict__ KS, const u16* __restrict__ QV,
               u16* __restrict__ Xout,
               const float* __restrict__ Wk3, const float* __restrict__ Wq3,
               const float* __restrict__ Wv3, const float* __restrict__ Ws3,
               const float* __restrict__ b3,
               float* __restrict__ k3, float2* __restrict__ qv3,
               float* __restrict__ s3, int N)
{
    const int lane = threadIdx.x & 63;
    const int half = lane >> 5;
    const int t    = lane & 31;       // channel group: channels 4t..4t+3
    int gw = blockIdx.x * (blockDim.x >> 6) + (threadIdx.x >> 6);
    int nw = gridDim.x * (blockDim.x >> 6);

    float4 wk4, wq4, wv4, ws4;
    float bias3 = 0.0f;
    if (MODE == 1) {
        wk4 = *(const float4*)(Wk3 + 4 * t);
        wq4 = *(const float4*)(Wq3 + 4 * t);
        wv4 = *(const float4*)(Wv3 + 4 * t);
        ws4 = *(const float4*)(Ws3 + 4 * t);
        bias3 = b3[0];
    }

#define LOAD2(S0, S1) (*((const uint4*)(QV + (size_t)(half ? (S1) : (S0)) * 256) + t))
#define COMP(QVv, A0, A1, A2, A3)                                             \
    {                                                                         \
        float q0_, q1_, q2_, q3_, v0_, v1_, v2_, v3_;                         \
        bfu2((QVv).x, q0_, q1_); bfu2((QVv).y, q2_, q3_);                     \
        bfu2((QVv).z, v0_, v1_); bfu2((QVv).w, v2_, v3_);                     \
        A0 += gate(k0 + q0_) * v0_;  A1 += gate(k1 + q1_) * v1_;              \
        A2 += gate(k2 + q2_) * v2_;  A3 += gate(k3v + q3_) * v3_;             \
    }

    for (int d = gw; d < N; d += nw) {
        int beg = rowp[d], end = rowp[d + 1];
        uint2 kk = *(const uint2*)(KS + (size_t)d * 256 + t * 4);
        float k0, k1, k2, k3v;
        bfu2(kk.x, k0, k1); bfu2(kk.y, k2, k3v);
        float a0 = 0.f, a1 = 0.f, a2 = 0.f, a3 = 0.f;
        float e0 = 0.f, e1 = 0.f, e2 = 0.f, e3 = 0.f;

        for (int base = beg; base < end; base += 64) {
            int e = base + lane;
            int sv = (e < end) ? ssrc[e] : 0;
            int m = end - base; if (m > 64) m = 64;
            int j = 0;
            for (; j + 4 <= m; j += 4) {
                int sa0 = __builtin_amdgcn_readlane(sv, j);
                int sa1 = __builtin_amdgcn_readlane(sv, j + 1);
                int sb0 = __builtin_amdgcn_readlane(sv, j + 2);
                int sb1 = __builtin_amdgcn_readlane(sv, j + 3);
                uint4 qA = LOAD2(sa0, sa1);
                uint4 qB = LOAD2(sb0, sb1);
                COMP(qA, a0, a1, a2, a3);
                COMP(qB, e0, e1, e2, e3);
            }
            if (j + 2 <= m) {
                int s0 = __builtin_amdgcn_readlane(sv, j);
                int s1 = __builtin_amdgcn_readlane(sv, j + 1);
                uint4 qA = LOAD2(s0, s1);
                COMP(qA, a0, a1, a2, a3);
                j += 2;
            }
            if (j < m) {  // single odd edge: only half 0 accumulates
                int s0i = __builtin_amdgcn_readlane(sv, j);
                uint4 qv_ = *((const uint4*)(QV + (size_t)s0i * 256) + t);
                float q0_, q1_, q2_, q3_, v0_, v1_, v2_, v3_;
                bfu2(qv_.x, q0_, q1_); bfu2(qv_.y, q2_, q3_);
                bfu2(qv_.z, v0_, v1_); bfu2(qv_.w, v2_, v3_);
                if (half == 0) {
                    a0 += gate(k0 + q0_) * v0_;  a1 += gate(k1 + q1_) * v1_;
                    a2 += gate(k2 + q2_) * v2_;  a3 += gate(k3v + q3_) * v3_;
                }
            }
        }
#undef LOAD2
#undef COMP

        a0 += e0; a1 += e1; a2 += e2; a3 += e3;
        a0 += __shfl_xor(a0, 32);
        a1 += __shfl_xor(a1, 32);
        a2 += __shfl_xor(a2, 32);
        a3 += __shfl_xor(a3, 32);

        uint2 ss = *(const uint2*)(KS + (size_t)d * 256 + 128 + t * 4);
        float s0f, s1f, s2f, s3f;
        bfu2(ss.x, s0f, s1f); bfu2(ss.y, s2f, s3f);
        float r0 = fmaxf(s0f + a0, 0.f);
        float r1 = fmaxf(s1f + a1, 0.f);
        float r2 = fmaxf(s2f + a2, 0.f);
        float r3 = fmaxf(s3f + a3, 0.f);

        if (MODE == 0) {
            if (half == 0) {
                uint2 st;
                st.x = ((u32)f2bf(r1) << 16) | f2bf(r0);
                st.y = ((u32)f2bf(r3) << 16) | f2bf(r2);
                *(uint2*)(Xout + (size_t)d * 128 + t * 4) = st;
            }
        } else {
            float pk = r0 * wk4.x + r1 * wk4.y + r2 * wk4.z + r3 * wk4.w;
            float pq = r0 * wq4.x + r1 * wq4.y + r2 * wq4.z + r3 * wq4.w;
            float pv = r0 * wv4.x + r1 * wv4.y + r2 * wv4.z + r3 * wv4.w;
            float ps = r0 * ws4.x + r1 * ws4.y + r2 * ws4.z + r3 * ws4.w;
            for (int off = 1; off < 32; off <<= 1) {
                pk += __shfl_xor(pk, off);
                pq += __shfl_xor(pq, off);
                pv += __shfl_xor(pv, off);
                ps += __shfl_xor(ps, off);
            }
            if (lane == 0) {
                k3[d]  = NEG_LOG2E * pk;
                qv3[d] = make_float2(NEG_LOG2E * pq, pv);
                s3[d]  = ps + bias3;
            }
        }
    }
}

// ---------------------------------------------------------------------------
// CSR edge phase, Dout=1: wave per node; qv3 packed float2 (one 8B gather).
__global__ __launch_bounds__(256)
void edge3_csr(const int* __restrict__ rowp, const int* __restrict__ ssrc,
               const float* __restrict__ k3, const float2* __restrict__ qv3,
               const float* __restrict__ s3, float* __restrict__ outp, int N)
{
    int lane = threadIdx.x & 63;
    int gw = blockIdx.x * (blockDim.x >> 6) + (threadIdx.x >> 6);
    int nw = gridDim.x * (blockDim.x >> 6);
    for (int d = gw; d < N; d += nw) {
        int beg = rowp[d], end = rowp[d + 1];
        float kd = k3[d];
        float sum = 0.0f;
        for (int e = beg + lane; e < end; e += 64) {
            float2 qv = qv3[ssrc[e]];
            sum += gate(kd + qv.x) * qv.y;
        }
        for (int off = 32; off > 0; off >>= 1) sum += __shfl_xor(sum, off);
        if (lane == 0) outp[d] = s3[d] + sum;
    }
}

// ---------------------------------------------------------------------------
extern "C" void kernel_launch(void* const* d_in, const int* in_sizes, int n_in,
                              void* d_out, int out_size, void* d_ws, size_t ws_size,
                              hipStream_t stream)
{
    const float* x0 = (const float*)d_in[0];
    const int*   ei = (const int*)d_in[1];
    const int    N  = in_sizes[0] / 128;   // 100000
    const int    E  = in_sizes[1] / 2;     // 1600000
    const int* src = ei;
    const int* dst = ei + E;

    const int NBUCK = (N + 255) >> 8;              // 391
    const int NA    = (E + CSR_CH - 1) / CSR_CH;   // 782
    const int M     = NBUCK * NA;                  // 305,762
    const int nparts = (M + 1023) / 1024;          // 299

    char* ws = (char*)d_ws;
    size_t off = 0;
    auto carve = [&](size_t bytes) { void* p = ws + off; off += (bytes + 255) & ~(size_t)255; return p; };
    u16*    Wt   = (u16*)carve((size_t)8 * 16384 * sizeof(u16));
    u16*    bufX = (u16*)carve((size_t)N * 128 * sizeof(u16));
    u16*    KS   = (u16*)carve((size_t)N * 256 * sizeof(u16));
    u16*    QV   = (u16*)carve((size_t)N * 256 * sizeof(u16));
    int*    ssrc = (int*)carve((size_t)E * sizeof(int));
    u32*    tkey = (u32*)carve((size_t)E * sizeof(u32));
    int*    rowp = (int*)carve((size_t)(N + 1) * sizeof(int));
    int*    cnt  = (int*)carve((size_t)M * sizeof(int));
    int*    scnt = (int*)carve((size_t)(M + 1) * sizeof(int));
    int*    part = (int*)carve((size_t)512 * sizeof(int));
    float*  k3   = (float*)carve((size_t)N * sizeof(float));
    float2* qv3  = (float2*)carve((size_t)N * sizeof(float2));
    float*  s3   = (float*)carve((size_t)N * sizeof(float));

    P8 wp;
    wp.p[0] = (const float*)d_in[2];  wp.p[1] = (const float*)d_in[3];
    wp.p[2] = (const float*)d_in[4];  wp.p[3] = (const float*)d_in[5];
    wp.p[4] = (const float*)d_in[7];  wp.p[5] = (const float*)d_in[8];
    wp.p[6] = (const float*)d_in[9];  wp.p[7] = (const float*)d_in[10];

    int gb = (N + 127) / 128;

    // 1: weight prep + coarse histogram (independent, one launch)
    prep_hist_k<<<64 + NA, 256, 0, stream>>>(wp, Wt, dst, cnt, E, NA, NBUCK);
    // 2-3: scan
    scan_part_k<<<nparts, 256, 0, stream>>>(cnt, part, M);
    scan_emit2_k<<<nparts, 256, 0, stream>>>(cnt, part, scnt, M, E, nparts);
    // 4: coarse scatter
    sortA_scat<<<NA, 256, 0, stream>>>(src, dst, scnt, tkey, E, NA, NBUCK);
    // 5: fine grouping + layer-1 GEMM (independent, one launch)
    sortB_gemm1<<<NBUCK + gb, 256, 0, stream>>>(tkey, scnt, rowp, ssrc, NA, N, E, NBUCK,
        x0, Wt, (const float*)d_in[6], KS, QV);
    // 6: layer-1 edge
    edge_csr2<0><<<4096, 256, 0, stream>>>(rowp, ssrc, KS, QV, bufX,
        nullptr, nullptr, nullptr, nullptr, nullptr, nullptr, nullptr, nullptr, N);
    // 7: layer-2 GEMM
    gemm_l2<<<gb, 256, 0, stream>>>(bufX, Wt + 4 * 16384, (const float*)d_in[11], KS, QV, N);
    // 8: layer-2 edge (+ fused layer-3 GEMV)
    edge_csr2<1><<<4096, 256, 0, stream>>>(rowp, ssrc, KS, QV, nullptr,
        (const float*)d_in[12], (const float*)d_in[13], (const float*)d_in[14],
        (const float*)d_in[15], (const float*)d_in[16],
        k3, qv3, s3, N);
    // 9: layer-3 edge -> d_out
    edge3_csr<<<2048, 256, 0, stream>>>(rowp, ssrc, k3, qv3, s3, (float*)d_out, N);
}